// Round 17
// baseline (25.436 us; speedup 1.0000x reference)
//
#include <hip/hip_runtime.h>
#include <math.h>

typedef _Float16 f16x8 __attribute__((ext_vector_type(8)));
typedef __fp16   fp16v2 __attribute__((ext_vector_type(2)));
typedef float    f32x16 __attribute__((ext_vector_type(16)));

#define THREADS 256
#define YCHUNK  4096  // y points per LDS chunk (32 KB)
#define XPB     128   // x points per block = 2 col-sets * 64

// Guarded no-AGPR hint (no-op if the attribute doesn't exist).
#if defined(__has_attribute)
#if __has_attribute(amdgpu_num_agpr)
#define NO_AGPR __attribute__((amdgpu_num_agpr(0)))
#endif
#endif
#ifndef NO_AGPR
#define NO_AGPR
#endif

static __device__ inline unsigned pk2(float a, float b) {
    fp16v2 h = __builtin_amdgcn_cvt_pkrtz(a, b);
    return __builtin_bit_cast(unsigned, h);
}

static __device__ inline void packwrite(uint2* dst, float4 f0, float4 f1,
                                        float4 f2) {
    float n0 = fmaf(f0.x, f0.x, fmaf(f0.y, f0.y, f0.z * f0.z));
    float n1 = fmaf(f0.w, f0.w, fmaf(f1.x, f1.x, f1.y * f1.y));
    float n2 = fmaf(f1.z, f1.z, fmaf(f1.w, f1.w, f2.x * f2.x));
    float n3 = fmaf(f2.y, f2.y, fmaf(f2.z, f2.z, f2.w * f2.w));
    dst[0] = make_uint2(pk2(f0.x, f0.y), pk2(f0.z, n0));
    dst[1] = make_uint2(pk2(f0.w, f1.x), pk2(f1.y, n1));
    dst[2] = make_uint2(pk2(f1.z, f1.w), pk2(f2.x, n2));
    dst[3] = make_uint2(pk2(f2.y, f2.z), pk2(f2.w, n3));
}

// R15 shell (wave = 64 x-cols via two B-frags x half the y rows; in-LDS
// merge). R16 change: MINIMAL-PRESSURE inner loop. R12/R15 forensics: the
// kernel is VALU-throughput bound at 24 VALU insts/MFMA, 16 of which are
// v_accvgpr_read because LLVM parks MFMA accumulators in AGPRs under
// pressure. Keep only 2 acc sets (32 regs) live, fold immediately, and
// forbid unrolling so the register allocator can emit VGPR-dest MFMA
// (gfx90a+ supports it) and the reads disappear.
__global__ NO_AGPR __launch_bounds__(THREADS, 2) void chamfer_kernel(
    const float* __restrict__ pred, const float* __restrict__ targ,
    float* __restrict__ partials, int N)
{
    const int dir = blockIdx.z;
    const float* xsrc = dir == 0 ? pred : targ;
    const float* ysrc = dir == 0 ? targ : pred;
    const int b = blockIdx.y;

    __shared__ uint2 sy[YCHUNK];
    __shared__ float sdm[2][XPB];   // [y-half][col] per-col mins (pre-merge)
    __shared__ float swave[2];

    const int tid  = threadIdx.x;
    const int lane = tid & 63;
    const int wave = tid >> 6;     // 0..3
    const int cs   = wave & 1;     // col-set (which 64 x-cols)
    const int h    = wave >> 1;    // y half
    const int col  = lane & 31;

    // Two x columns per lane (lanes 32-63 duplicate lanes 0-31).
    const int    xb  = blockIdx.x * XPB + cs * 64 + col;
    const size_t xiL = (size_t)(b * N + xb) * 3;
    const size_t xiH = (size_t)(b * N + xb + 32) * 3;
    const float xl0 = xsrc[xiL], xl1 = xsrc[xiL + 1], xl2 = xsrc[xiL + 2];
    const float xh0 = xsrc[xiH], xh1 = xsrc[xiH + 1], xh2 = xsrc[xiH + 2];

    const bool act = lane < 32;
    f16x8 bfl, bfh;
    bfl[0] = act ? (_Float16)(-2.0f * xl0) : (_Float16)0.0f;
    bfl[1] = act ? (_Float16)(-2.0f * xl1) : (_Float16)0.0f;
    bfl[2] = act ? (_Float16)(-2.0f * xl2) : (_Float16)0.0f;
    bfl[3] = act ? (_Float16)1.0f : (_Float16)0.0f;
    bfl[4] = bfl[5] = bfl[6] = bfl[7] = (_Float16)0.0f;
    bfh[0] = act ? (_Float16)(-2.0f * xh0) : (_Float16)0.0f;
    bfh[1] = act ? (_Float16)(-2.0f * xh1) : (_Float16)0.0f;
    bfh[2] = act ? (_Float16)(-2.0f * xh2) : (_Float16)0.0f;
    bfh[3] = act ? (_Float16)1.0f : (_Float16)0.0f;
    bfh[4] = bfh[5] = bfh[6] = bfh[7] = (_Float16)0.0f;

    f32x16 zacc;
    f32x16 vmin0, vmin1;
#pragma unroll
    for (int r = 0; r < 16; ++r) {
        zacc[r] = 0.0f; vmin0[r] = INFINITY; vmin1[r] = INFINITY;
    }

#define MF(X, BF)                                                          \
    __builtin_amdgcn_mfma_f32_32x32x16_f16(                                \
        __builtin_bit_cast(f16x8, make_uint4((X).x, (X).y, 0u, 0u)),       \
        BF, zacc, 0, 0, 0)

    const int nchunks = N / YCHUNK;   // 2
    for (int c = 0; c < nchunks; ++c) {
        __syncthreads();  // previous compute phase done reading sy
        {
            const float4* yf4 = (const float4*)(ysrc + (size_t)b * N * 3
                                                + (size_t)c * YCHUNK * 3);
#pragma unroll
            for (int k = 0; k < 4; ++k) {
                const int fb = k * THREADS * 3 + tid * 3;
                packwrite(&sy[(k * THREADS + tid) * 4], yf4[fb], yf4[fb + 1],
                          yf4[fb + 2]);
            }
        }
        __syncthreads();

        // This wave's y-half: 64 row-groups; one A-read feeds TWO MFMAs.
        // Only 2 acc sets live at any point; no unrolling (keep pressure
        // minimal so MFMA dests land in VGPRs).
        const int gb = h * 64;
#pragma unroll 1
        for (int g = 0; g < 64; g += 2) {
            uint2 a0 = sy[(gb + g) * 32 + col];
            uint2 a1 = sy[(gb + g + 1) * 32 + col];
            f32x16 m0 = MF(a0, bfl);
            f32x16 m1 = MF(a1, bfl);
#pragma unroll
            for (int r = 0; r < 16; ++r)
                vmin0[r] = fminf(fminf(vmin0[r], m0[r]), m1[r]);  // v_min3
            f32x16 m2 = MF(a0, bfh);
            f32x16 m3 = MF(a1, bfh);
#pragma unroll
            for (int r = 0; r < 16; ++r)
                vmin1[r] = fminf(fminf(vmin1[r], m2[r]), m3[r]);
        }
    }
#undef MF

    // Fold 16 regs -> 1, merge row-halves (lane^32), add |x|^2 in f32.
    float v0 = vmin0[0], v1 = vmin1[0];
#pragma unroll
    for (int r = 1; r < 16; ++r) {
        v0 = fminf(v0, vmin0[r]); v1 = fminf(v1, vmin1[r]);
    }
    v0 = fminf(v0, __shfl_xor(v0, 32));
    v1 = fminf(v1, __shfl_xor(v1, 32));
    const float dlo = v0 + fmaf(xl0, xl0, fmaf(xl1, xl1, xl2 * xl2));
    const float dhi = v1 + fmaf(xh0, xh0, fmaf(xh1, xh1, xh2 * xh2));

    if (act) {
        sdm[h][cs * 64 + col]      = dlo;
        sdm[h][cs * 64 + 32 + col] = dhi;
    }
    __syncthreads();

    // Merge the two y-halves per col, then sum 128 cols (waves 0-1).
    if (tid < 128) {
        float m = fminf(sdm[0][tid], sdm[1][tid]);
#pragma unroll
        for (int off = 32; off > 0; off >>= 1) m += __shfl_xor(m, off);
        if ((tid & 63) == 0) swave[tid >> 6] = m;
    }
    __syncthreads();
    if (tid == 0) {
        int bid = blockIdx.x + gridDim.x * (blockIdx.y + gridDim.y * blockIdx.z);
        partials[bid] = swave[0] + swave[1];
    }
}

// Sum all 512 block partials; dist = sum / (B*N); out = (loss, dist, rate).
__global__ __launch_bounds__(512) void finalize(
    const float* __restrict__ partials, const float* __restrict__ fbpp,
    float* __restrict__ out, int nPartials, int totalPts)
{
    __shared__ float sw[8];
    const int tid = threadIdx.x;
    float v = (tid < nPartials) ? partials[tid] : 0.0f;
#pragma unroll
    for (int off = 32; off > 0; off >>= 1) v += __shfl_xor(v, off);
    if ((tid & 63) == 0) sw[tid >> 6] = v;
    __syncthreads();
    if (tid == 0) {
        float t = 0.0f;
#pragma unroll
        for (int w = 0; w < 8; ++w) t += sw[w];
        float dist = t / (float)totalPts;
        float rate = fbpp[0];
        out[0] = dist + rate;
        out[1] = dist;
        out[2] = rate;
    }
}

extern "C" void kernel_launch(void* const* d_in, const int* in_sizes, int n_in,
                              void* d_out, int out_size, void* d_ws, size_t ws_size,
                              hipStream_t stream) {
    const float* pred = (const float*)d_in[0];
    const float* targ = (const float*)d_in[1];
    const float* fbpp = (const float*)d_in[2];
    float* out = (float*)d_out;

    const int B = 4;
    const int N = in_sizes[0] / (B * 3);   // 8192
    float* partials = (float*)d_ws;        // 512 floats

    dim3 grid(N / XPB, B, 2);              // (64, 4, 2) = 512 blocks
    chamfer_kernel<<<grid, THREADS, 0, stream>>>(pred, targ, partials, N);

    const int nPartials = (N / XPB) * B * 2;  // 512
    finalize<<<1, 512, 0, stream>>>(partials, fbpp, out, nPartials, B * N);
}

// Round 20
// 23.286 us; speedup vs baseline: 1.0923x; 1.0923x over previous
//
#include <hip/hip_runtime.h>
#include <math.h>

typedef _Float16 f16x8 __attribute__((ext_vector_type(8)));
typedef __fp16   fp16v2 __attribute__((ext_vector_type(2)));
typedef float    f32x16 __attribute__((ext_vector_type(16)));

#define THREADS 256
#define YCHUNK  4096  // y points per LDS chunk (32 KB)
#define XPB     128   // x points per block = 2 col-sets * 64

static __device__ inline unsigned pk2(float a, float b) {
    fp16v2 h = __builtin_amdgcn_cvt_pkrtz(a, b);
    return __builtin_bit_cast(unsigned, h);
}

static __device__ inline void packwrite(uint2* dst, float4 f0, float4 f1,
                                        float4 f2) {
    float n0 = fmaf(f0.x, f0.x, fmaf(f0.y, f0.y, f0.z * f0.z));
    float n1 = fmaf(f0.w, f0.w, fmaf(f1.x, f1.x, f1.y * f1.y));
    float n2 = fmaf(f1.z, f1.z, fmaf(f1.w, f1.w, f2.x * f2.x));
    float n3 = fmaf(f2.y, f2.y, fmaf(f2.z, f2.z, f2.w * f2.w));
    dst[0] = make_uint2(pk2(f0.x, f0.y), pk2(f0.z, n0));
    dst[1] = make_uint2(pk2(f0.w, f1.x), pk2(f1.y, n1));
    dst[2] = make_uint2(pk2(f1.z, f1.w), pk2(f2.x, n2));
    dst[3] = make_uint2(pk2(f2.y, f2.z), pk2(f2.w, n3));
}

// R18 post-mortem closed the asm path (two hazard directions uncoverable at
// source level). This round: INTRINSICS-ONLY ping-pong — fold D-set issued
// one full phase earlier while the current phase's 4 MFMAs occupy the
// matrix pipe, so the ~10.3us VALU stream (incl. the compiler-forced
// accvgpr-read tax) overlaps the ~7.1us MFMA stream instead of serializing.
// Topology = R15 best-known (wave: 64 x-cols via 2 B-frags, half the y).
__global__ __launch_bounds__(THREADS, 2) void chamfer_kernel(
    const float* __restrict__ pred, const float* __restrict__ targ,
    float* __restrict__ partials, int N)
{
    const int dir = blockIdx.z;
    const float* xsrc = dir == 0 ? pred : targ;
    const float* ysrc = dir == 0 ? targ : pred;
    const int b = blockIdx.y;

    __shared__ uint2 sy[YCHUNK];
    __shared__ float sdm[2][XPB];   // [y-half][col] per-col mins (pre-merge)
    __shared__ float swave[2];

    const int tid  = threadIdx.x;
    const int lane = tid & 63;
    const int wave = tid >> 6;     // 0..3
    const int cs   = wave & 1;     // col-set (which 64 x-cols)
    const int h    = wave >> 1;    // y half
    const int col  = lane & 31;

    // Two x columns per lane (lanes 32-63 carry K slots 8..15: zeros).
    const int    xb  = blockIdx.x * XPB + cs * 64 + col;
    const size_t xiL = (size_t)(b * N + xb) * 3;
    const size_t xiH = (size_t)(b * N + xb + 32) * 3;
    const float xl0 = xsrc[xiL], xl1 = xsrc[xiL + 1], xl2 = xsrc[xiL + 2];
    const float xh0 = xsrc[xiH], xh1 = xsrc[xiH + 1], xh2 = xsrc[xiH + 2];

    const bool act = lane < 32;
    f16x8 bfl, bfh;
    bfl[0] = act ? (_Float16)(-2.0f * xl0) : (_Float16)0.0f;
    bfl[1] = act ? (_Float16)(-2.0f * xl1) : (_Float16)0.0f;
    bfl[2] = act ? (_Float16)(-2.0f * xl2) : (_Float16)0.0f;
    bfl[3] = act ? (_Float16)1.0f : (_Float16)0.0f;
    bfl[4] = bfl[5] = bfl[6] = bfl[7] = (_Float16)0.0f;
    bfh[0] = act ? (_Float16)(-2.0f * xh0) : (_Float16)0.0f;
    bfh[1] = act ? (_Float16)(-2.0f * xh1) : (_Float16)0.0f;
    bfh[2] = act ? (_Float16)(-2.0f * xh2) : (_Float16)0.0f;
    bfh[3] = act ? (_Float16)1.0f : (_Float16)0.0f;
    bfh[4] = bfh[5] = bfh[6] = bfh[7] = (_Float16)0.0f;

    f32x16 zacc;
    f32x16 vmin0, vmin1;
#pragma unroll
    for (int r = 0; r < 16; ++r) {
        zacc[r] = 0.0f; vmin0[r] = INFINITY; vmin1[r] = INFINITY;
    }

#define MF(X, BF)                                                          \
    __builtin_amdgcn_mfma_f32_32x32x16_f16(                                \
        __builtin_bit_cast(f16x8, make_uint4((X).x, (X).y, 0u, 0u)),       \
        BF, zacc, 0, 0, 0)

// Issue one phase: row-group pair (g, g+1) x both B-frags -> 4 MFMAs.
#define PHASE(P, g)                                                        \
    {                                                                      \
        uint2 q0 = sy[(gb + (g)) * 32 + col];                              \
        uint2 q1 = sy[(gb + (g) + 1) * 32 + col];                          \
        P##0 = MF(q0, bfl); P##1 = MF(q1, bfl);                            \
        P##2 = MF(q0, bfh); P##3 = MF(q1, bfh);                            \
    }

#define FOLDP(P)                                                           \
    {                                                                      \
        _Pragma("unroll")                                                  \
        for (int r = 0; r < 16; ++r) {                                     \
            vmin0[r] = fminf(fminf(vmin0[r], P##0[r]), P##1[r]);           \
            vmin1[r] = fminf(fminf(vmin1[r], P##2[r]), P##3[r]);           \
        }                                                                  \
    }

    const int nchunks = N / YCHUNK;   // 2
    for (int c = 0; c < nchunks; ++c) {
        __syncthreads();  // previous compute phase done reading sy
        {
            const float4* yf4 = (const float4*)(ysrc + (size_t)b * N * 3
                                                + (size_t)c * YCHUNK * 3);
#pragma unroll
            for (int k = 0; k < 4; ++k) {
                const int fb = k * THREADS * 3 + tid * 3;
                packwrite(&sy[(k * THREADS + tid) * 4], yf4[fb], yf4[fb + 1],
                          yf4[fb + 2]);
            }
        }
        __syncthreads();

        // 64 row-groups = 32 pair-phases; depth-1 ping-pong: fold the
        // phase issued previously while this phase occupies the matrix pipe.
        const int gb = h * 64;
        f32x16 pA0, pA1, pA2, pA3, pB0, pB1, pB2, pB3;
        PHASE(pA, 0);
#pragma unroll 1
        for (int g = 2; g <= 58; g += 4) {
            PHASE(pB, g);
            FOLDP(pA);
            PHASE(pA, g + 2);
            FOLDP(pB);
        }
        PHASE(pB, 62);
        FOLDP(pA);
        FOLDP(pB);
    }
#undef MF
#undef PHASE
#undef FOLDP

    // Fold 16 regs -> 1, merge row-halves (lane^32), add |x|^2 in f32.
    float v0 = vmin0[0], v1 = vmin1[0];
#pragma unroll
    for (int r = 1; r < 16; ++r) {
        v0 = fminf(v0, vmin0[r]); v1 = fminf(v1, vmin1[r]);
    }
    v0 = fminf(v0, __shfl_xor(v0, 32));
    v1 = fminf(v1, __shfl_xor(v1, 32));
    const float dlo = v0 + fmaf(xl0, xl0, fmaf(xl1, xl1, xl2 * xl2));
    const float dhi = v1 + fmaf(xh0, xh0, fmaf(xh1, xh1, xh2 * xh2));

    if (act) {
        sdm[h][cs * 64 + col]      = dlo;
        sdm[h][cs * 64 + 32 + col] = dhi;
    }
    __syncthreads();

    // Merge the two y-halves per col, then sum 128 cols (waves 0-1).
    if (tid < 128) {
        float m = fminf(sdm[0][tid], sdm[1][tid]);
#pragma unroll
        for (int off = 32; off > 0; off >>= 1) m += __shfl_xor(m, off);
        if ((tid & 63) == 0) swave[tid >> 6] = m;
    }
    __syncthreads();
    if (tid == 0) {
        int bid = blockIdx.x + gridDim.x * (blockIdx.y + gridDim.y * blockIdx.z);
        partials[bid] = swave[0] + swave[1];
    }
}

// Sum all 512 block partials; dist = sum / (B*N); out = (loss, dist, rate).
__global__ __launch_bounds__(512) void finalize(
    const float* __restrict__ partials, const float* __restrict__ fbpp,
    float* __restrict__ out, int nPartials, int totalPts)
{
    __shared__ float sw[8];
    const int tid = threadIdx.x;
    float v = (tid < nPartials) ? partials[tid] : 0.0f;
#pragma unroll
    for (int off = 32; off > 0; off >>= 1) v += __shfl_xor(v, off);
    if ((tid & 63) == 0) sw[tid >> 6] = v;
    __syncthreads();
    if (tid == 0) {
        float t = 0.0f;
#pragma unroll
        for (int w = 0; w < 8; ++w) t += sw[w];
        float dist = t / (float)totalPts;
        float rate = fbpp[0];
        out[0] = dist + rate;
        out[1] = dist;
        out[2] = rate;
    }
}

extern "C" void kernel_launch(void* const* d_in, const int* in_sizes, int n_in,
                              void* d_out, int out_size, void* d_ws, size_t ws_size,
                              hipStream_t stream) {
    const float* pred = (const float*)d_in[0];
    const float* targ = (const float*)d_in[1];
    const float* fbpp = (const float*)d_in[2];
    float* out = (float*)d_out;

    const int B = 4;
    const int N = in_sizes[0] / (B * 3);   // 8192
    float* partials = (float*)d_ws;        // 512 floats

    dim3 grid(N / XPB, B, 2);              // (64, 4, 2) = 512 blocks
    chamfer_kernel<<<grid, THREADS, 0, stream>>>(pred, targ, partials, N);

    const int nPartials = (N / XPB) * B * 2;  // 512
    finalize<<<1, 512, 0, stream>>>(partials, fbpp, out, nPartials, B * N);
}